// Round 13
// baseline (81.828 us; speedup 1.0000x reference)
//
#include <hip/hip_runtime.h>

#define T_STEPS 100
#define BATCH 256
#define NIN 784
#define N0 64
#define N1 64
#define N2 10
#define CHUNK (BATCH*N0 + BATCH*N1 + BATCH*N2)   // 35328

typedef __attribute__((ext_vector_type(8))) short short8;
typedef __attribute__((ext_vector_type(4))) float f32x4;

__device__ inline short bf16_rne(float x) {
  unsigned u = __float_as_uint(x);
  unsigned h = (u + 0x7FFFu + ((u >> 16) & 1u)) >> 16;
  return (short)h;
}
__device__ inline float bf16_val(short h) {
  return __uint_as_float(((unsigned)(unsigned short)h) << 16);
}

// ---------------------------------------------------------------------------
// Kernel 0: pack W0 (f32 [64][784]) into bf16x3 fragment-coalesced layout
// W0p[c][p][ct][lane][e], c = 32-k chunk (25 of them, zero-pad k>=784),
// lane = MFMA B-frag lane (col = ct*16 + (l&15), k = c*32 + (l>>4)*8 + e).
// Identical to R12's prep (passed absmax 0).
// ---------------------------------------------------------------------------
__global__ __launch_bounds__(256) void prep_w0_pack(
    const float* __restrict__ W0, short* __restrict__ W0p) {
  int idx = blockIdx.x * 256 + threadIdx.x;      // 0..153599
  int e  = idx & 7;
  int r1 = idx >> 3;
  int l  = r1 & 63;
  int r2 = r1 >> 6;
  int ct = r2 & 3;
  int r3 = r2 >> 2;
  int p  = r3 % 3;
  int c  = r3 / 3;                               // 0..24
  int k   = c * 32 + (l >> 4) * 8 + e;
  int col = ct * 16 + (l & 15);
  float w = (k < NIN) ? W0[col * NIN + k] : 0.0f;
  short h0 = bf16_rne(w);
  float rr1 = w - bf16_val(h0);
  short h1 = bf16_rne(rr1);
  float rr2 = rr1 - bf16_val(h1);
  short h2 = bf16_rne(rr2);
  W0p[idx] = (p == 0) ? h0 : (p == 1) ? h1 : h2;
}

// ---------------------------------------------------------------------------
// Kernel 1: the whole SNN, one block per batch element b.
// Phase A: I0[b] = X[:,b,:] @ W0^T + b0 via bf16x3 MFMA straight into LDS
//   bufA. 7 t-tiles (112 rows, t>=100 zero-padded) split over 4 waves
//   (w0:{0,4} w1:{1,5} w2:{2,6} w3:{3}). B-frags from packed W0p (coalesced,
//   L1/L2-hot); A-frags: predicated X loads + in-register bf16x3 convert.
//   25 k-chunks, k ascending, 6-product order as R8-R12; bias added last.
// Phase B: scan0 -> GEMM1 -> scan1 -> GEMM2 -> scan2 (proven fused body).
// ---------------------------------------------------------------------------
__global__ __launch_bounds__(256) void snn_kernel(
    const float* __restrict__ X, const short* __restrict__ W0p,
    const float* __restrict__ b0,
    const float* __restrict__ W1, const float* __restrict__ b1,
    const float* __restrict__ W2, const float* __restrict__ b2,
    float* __restrict__ out) {
  __shared__ float bufA[112][68];       // I0 -> z0 -> I1 -> z1 (in place)
  __shared__ float sW1t[64][68];        // W1 transposed [j][i]
  __shared__ float sW2[N2][68];
  __shared__ float sI2[T_STEPS][N2];

  const int b   = blockIdx.x;
  const int tid = threadIdx.x;
  const int wid = tid >> 6;
  const int l   = tid & 63;
  const int lr  = l & 15;
  const int lk  = l >> 4;
  const int j   = tid & 63;
  const int tq  = tid >> 6;
  float* outSpk = out;
  float* laySpk = out + T_STEPS * BATCH * N2;

  // ================= Phase A: GEMM0 into bufA =================
  const int tile0 = wid;                         // 0..3
  const int tile1 = wid + 4;                     // 4..7 (valid if <7)
  const int nt    = (tile1 < 7) ? 2 : 1;

  f32x4 acc[2][4];
#pragma unroll
  for (int i = 0; i < 2; ++i)
#pragma unroll
    for (int ct = 0; ct < 4; ++ct) acc[i][ct] = f32x4{0.f, 0.f, 0.f, 0.f};

  const short8* wp8 = (const short8*)W0p;
  const float4  z4  = {0.f, 0.f, 0.f, 0.f};
  const int t0g = tile0 * 16 + lr;               // global t of row-lane, tile 0
  const int t1g = tile1 * 16 + lr;

  for (int c = 0; c < 25; ++c) {
    const int kb = c * 32;
    const int k0 = kb + lk * 8;
    const bool kok = (k0 < NIN);                 // k0 % 8 == 0 -> k0+8 <= 784

    // ---- B loads: 12 coalesced 1KB loads (shared across waves -> L1)
    short8 cb[4][3];
#pragma unroll
    for (int ct = 0; ct < 4; ++ct)
#pragma unroll
      for (int p = 0; p < 3; ++p)
        cb[ct][p] = wp8[(size_t)((c * 3 + p) * 4 + ct) * 64 + l];

    // ---- A loads (predicated) + in-register bf16x3 convert
    short8 af[2][3];
#pragma unroll
    for (int i = 0; i < 2; ++i) {
      if (i >= nt) break;
      const int t = (i == 0) ? t0g : t1g;
      const bool ok = kok && (t < T_STEPS);
      const float* xp = X + ((size_t)t * BATCH + b) * NIN + k0;
      float4 xa = ok ? *(const float4*)(xp)     : z4;
      float4 xb = ok ? *(const float4*)(xp + 4) : z4;
      float xs[8] = {xa.x, xa.y, xa.z, xa.w, xb.x, xb.y, xb.z, xb.w};
#pragma unroll
      for (int e = 0; e < 8; ++e) {
        float x  = xs[e];
        short h0 = bf16_rne(x);   float rr1 = x - bf16_val(h0);
        short h1 = bf16_rne(rr1); float rr2 = rr1 - bf16_val(h1);
        af[i][0][e] = h0; af[i][1][e] = h1; af[i][2][e] = bf16_rne(rr2);
      }
    }

    // ---- MFMA: nt tiles x 4 col-tiles x 6 products (R8-R12 order)
#pragma unroll
    for (int i = 0; i < 2; ++i) {
      if (i >= nt) break;
#pragma unroll
      for (int ct = 0; ct < 4; ++ct) {
        f32x4 a = acc[i][ct];
        a = __builtin_amdgcn_mfma_f32_16x16x32_bf16(af[i][2], cb[ct][0], a, 0, 0, 0);
        a = __builtin_amdgcn_mfma_f32_16x16x32_bf16(af[i][0], cb[ct][2], a, 0, 0, 0);
        a = __builtin_amdgcn_mfma_f32_16x16x32_bf16(af[i][1], cb[ct][1], a, 0, 0, 0);
        a = __builtin_amdgcn_mfma_f32_16x16x32_bf16(af[i][1], cb[ct][0], a, 0, 0, 0);
        a = __builtin_amdgcn_mfma_f32_16x16x32_bf16(af[i][0], cb[ct][1], a, 0, 0, 0);
        a = __builtin_amdgcn_mfma_f32_16x16x32_bf16(af[i][0], cb[ct][0], a, 0, 0, 0);
        acc[i][ct] = a;
      }
    }
  }

  // ---- write I0 (+bias) into bufA. C/D: col = l&15, row = (l>>4)*4 + r
  {
    float bv[4];
#pragma unroll
    for (int ct = 0; ct < 4; ++ct) bv[ct] = b0[ct * 16 + lr];
#pragma unroll
    for (int i = 0; i < 2; ++i) {
      if (i >= nt) break;
      const int trow = ((i == 0) ? tile0 : tile1) * 16 + lk * 4;
#pragma unroll
      for (int ct = 0; ct < 4; ++ct)
#pragma unroll
        for (int r = 0; r < 4; ++r)
          bufA[trow + r][ct * 16 + lr] = acc[i][ct][r] + bv[ct];
    }
  }
  __syncthreads();

  // ================= Phase B (proven fused body) =================
  // ---- scan0 (wave 0, batched) || W1/W2 staging (waves 1-3)
  if (tq == 0) {
    float v = 0.0f;
#pragma unroll
    for (int g = 0; g < 4; ++g) {
      float ic[25];
#pragma unroll
      for (int i = 0; i < 25; ++i) ic[i] = bufA[g * 25 + i][j];
#pragma unroll
      for (int i = 0; i < 25; ++i) {
        v = v + 0.05f * ((0.0f - v) + ic[i]);
        float z = (v > 1.0f) ? 1.0f : 0.0f;
        v -= z;
        ic[i] = z;
      }
#pragma unroll
      for (int i = 0; i < 25; ++i) bufA[g * 25 + i][j] = ic[i];
    }
  } else {
    for (int idx = tid - 64; idx < 64 * 16; idx += 192) {
      int i = idx >> 4, jv = idx & 15;
      float4 wv = *(const float4*)(W1 + (size_t)i * 64 + jv * 4);
      sW1t[jv * 4 + 0][i] = wv.x;
      sW1t[jv * 4 + 1][i] = wv.y;
      sW1t[jv * 4 + 2][i] = wv.z;
      sW1t[jv * 4 + 3][i] = wv.w;
    }
    for (int idx = tid - 64; idx < N2 * 16; idx += 192) {
      int o = idx >> 4, jv = idx & 15;
      *(float4*)&sW2[o][jv * 4] = *(const float4*)(W2 + (size_t)o * 64 + jv * 4);
    }
  }
  __syncthreads();

  // ---- z0 -> layer_spikes
  for (int idx = tid; idx < T_STEPS * 16; idx += 256) {
    int t = idx >> 4, jv = idx & 15;
    *(float4*)(laySpk + (size_t)t * CHUNK + b * 64 + jv * 4) =
        *(const float4*)&bufA[t][jv * 4];
  }

  // ---- GEMM1: I1[t][i] = b1[i] + sum_j z0[t][j]*W1[i][j]
  const int iq = tid & 15;
  const int ts = tid >> 4;
  float g1[4][7];
  {
    float4 bias = *(const float4*)(b1 + iq * 4);
#pragma unroll
    for (int tt = 0; tt < 7; ++tt) {
      g1[0][tt] = bias.x; g1[1][tt] = bias.y; g1[2][tt] = bias.z; g1[3][tt] = bias.w;
    }
#pragma unroll
    for (int jq = 0; jq < 16; ++jq) {
      float4 zv4[7];
#pragma unroll
      for (int tt = 0; tt < 7; ++tt)
        zv4[tt] = *(const float4*)&bufA[ts * 7 + tt][jq * 4];
      float4 w4[4];
#pragma unroll
      for (int e = 0; e < 4; ++e)
        w4[e] = *(const float4*)&sW1t[jq * 4 + e][iq * 4];
#pragma unroll
      for (int e = 0; e < 4; ++e) {
#pragma unroll
        for (int tt = 0; tt < 7; ++tt) {
          float zv = ((const float*)&zv4[tt])[e];
          g1[0][tt] = fmaf(zv, w4[e].x, g1[0][tt]);
          g1[1][tt] = fmaf(zv, w4[e].y, g1[1][tt]);
          g1[2][tt] = fmaf(zv, w4[e].z, g1[2][tt]);
          g1[3][tt] = fmaf(zv, w4[e].w, g1[3][tt]);
        }
      }
    }
  }
  __syncthreads();            // all z0 reads complete
#pragma unroll
  for (int tt = 0; tt < 7; ++tt) {
    float4 o = {g1[0][tt], g1[1][tt], g1[2][tt], g1[3][tt]};
    *(float4*)&bufA[ts * 7 + tt][iq * 4] = o;
  }
  __syncthreads();

  // ---- scan1 (wave 0, batched)
  if (tq == 0) {
    float v = 0.0f;
#pragma unroll
    for (int g = 0; g < 4; ++g) {
      float ic[25];
#pragma unroll
      for (int i = 0; i < 25; ++i) ic[i] = bufA[g * 25 + i][j];
#pragma unroll
      for (int i = 0; i < 25; ++i) {
        v = v + 0.05f * ((0.0f - v) + ic[i]);
        float z = (v > 1.0f) ? 1.0f : 0.0f;
        v -= z;
        ic[i] = z;
      }
#pragma unroll
      for (int i = 0; i < 25; ++i) bufA[g * 25 + i][j] = ic[i];
    }
  }
  __syncthreads();

  // ---- z1 -> layer_spikes
  for (int idx = tid; idx < T_STEPS * 16; idx += 256) {
    int t = idx >> 4, jv = idx & 15;
    *(float4*)(laySpk + (size_t)t * CHUNK + BATCH * N0 + b * 64 + jv * 4) =
        *(const float4*)&bufA[t][jv * 4];
  }

  // ---- GEMM2: I2[t][o] = b2[o] + sum_j z1[t][j]*W2[o][j]
  for (int idx = tid; idx < T_STEPS * N2; idx += 256) {
    int t = idx / N2, o = idx % N2;
    float a = b2[o];
#pragma unroll
    for (int jq = 0; jq < 16; ++jq) {
      float4 z = *(const float4*)&bufA[t][jq * 4];
      float4 wv = *(const float4*)&sW2[o][jq * 4];
      a += z.x * wv.x;
      a += z.y * wv.y;
      a += z.z * wv.z;
      a += z.w * wv.w;
    }
    sI2[t][o] = a;
  }
  __syncthreads();

  // ---- scan2 (10 chains, batched)
  if (tid < N2) {
    float v = 0.0f;
#pragma unroll
    for (int g = 0; g < 4; ++g) {
      float ic[25];
#pragma unroll
      for (int i = 0; i < 25; ++i) ic[i] = sI2[g * 25 + i][tid];
#pragma unroll
      for (int i = 0; i < 25; ++i) {
        v = v + 0.05f * ((0.0f - v) + ic[i]);
        float z = (v > 1.0f) ? 1.0f : 0.0f;
        v -= z;
        ic[i] = z;
      }
#pragma unroll
      for (int i = 0; i < 25; ++i) sI2[g * 25 + i][tid] = ic[i];
    }
  }
  __syncthreads();

  // ---- z2 -> out_spikes + layer_spikes
  for (int idx = tid; idx < T_STEPS * N2; idx += 256) {
    int t = idx / N2, o = idx % N2;
    float z = sI2[t][o];
    outSpk[(size_t)t * (BATCH * N2) + b * N2 + o] = z;
    laySpk[(size_t)t * CHUNK + BATCH * (N0 + N1) + b * N2 + o] = z;
  }
}

extern "C" void kernel_launch(void* const* d_in, const int* in_sizes, int n_in,
                              void* d_out, int out_size, void* d_ws, size_t ws_size,
                              hipStream_t stream) {
  const float* inp = (const float*)d_in[0];
  const float* W0  = (const float*)d_in[1];
  const float* b0  = (const float*)d_in[2];
  const float* W1  = (const float*)d_in[3];
  const float* b1  = (const float*)d_in[4];
  const float* W2  = (const float*)d_in[5];
  const float* b2  = (const float*)d_in[6];

  short* W0p = (short*)d_ws;                 // 300 KB packed bf16x3 fragments

  prep_w0_pack<<<dim3(600), dim3(256), 0, stream>>>(W0, W0p);
  snn_kernel<<<dim3(BATCH), dim3(256), 0, stream>>>(inp, W0p, b0, W1, b1,
                                                    W2, b2, (float*)d_out);
}

// Round 14
// 60.184 us; speedup vs baseline: 1.3596x; 1.3596x over previous
//
#include <hip/hip_runtime.h>

#define T_STEPS 100
#define BATCH 256
#define NIN 784
#define N0 64
#define N1 64
#define N2 10
#define CHUNK (BATCH*N0 + BATCH*N1 + BATCH*N2)   // 35328
#define I0ELEMS (25600*64)

typedef __attribute__((ext_vector_type(8))) short short8;
typedef __attribute__((ext_vector_type(4))) float f32x4;

__device__ inline short bf16_rne(float x) {
  unsigned u = __float_as_uint(x);
  unsigned h = (u + 0x7FFFu + ((u >> 16) & 1u)) >> 16;
  return (short)h;
}
__device__ inline float bf16_val(short h) {
  return __uint_as_float(((unsigned)(unsigned short)h) << 16);
}

// ---------------------------------------------------------------------------
// Kernel 0: pack W0 (f32 [64][784]) into bf16x3 fragment-coalesced layout
// W0p[c][p][ct][lane][e]: c = 32-k chunk (25, zero-pad k>=784), lane = MFMA
// B-frag lane (col = ct*16 + (l&15), k = c*32 + (l>>4)*8 + e). (R12, passed.)
// ---------------------------------------------------------------------------
__global__ __launch_bounds__(256) void prep_w0_pack(
    const float* __restrict__ W0, short* __restrict__ W0p) {
  int idx = blockIdx.x * 256 + threadIdx.x;      // 0..153599
  int e  = idx & 7;
  int r1 = idx >> 3;
  int l  = r1 & 63;
  int r2 = r1 >> 6;
  int ct = r2 & 3;
  int r3 = r2 >> 2;
  int p  = r3 % 3;
  int c  = r3 / 3;                               // 0..24
  int k   = c * 32 + (l >> 4) * 8 + e;
  int col = ct * 16 + (l & 15);
  float w = (k < NIN) ? W0[col * NIN + k] : 0.0f;
  short h0 = bf16_rne(w);
  float rr1 = w - bf16_val(h0);
  short h1 = bf16_rne(rr1);
  float rr2 = rr1 - bf16_val(h1);
  short h2 = bf16_rne(rr2);
  W0p[idx] = (p == 0) ? h0 : (p == 1) ? h1 : h2;
}

// ---------------------------------------------------------------------------
// Kernel 1: I0T = X @ W0^T + b0 via bf16x3 MFMA — MAX-TLP design.
// Block = 16 rows x 64 cols, 8 waves (512 thr) = 8 k-splits {96x7, 112+16pad}.
// Grid 1600 -> 12800 waves; launch_bounds(512,8) forces VGPR<=64 so 8 waves
// co-reside per SIMD (LDS 34.8KB -> exactly 4 blocks/CU). Per-wave state kept
// minimal (acc 16 + A-frag 12 + per-ct B 12); latency hidden by TLP, not ILP.
// Epilogue: LDS reduce of the 8 wave-partials (s ascending + bias), b-major.
// ---------------------------------------------------------------------------
__global__ __launch_bounds__(512, 8) void gemm0_kernel(
    const float* __restrict__ X, const short* __restrict__ W0p,
    const float* __restrict__ b0, float* __restrict__ I0T) {
  __shared__ float red[8][16][68];               // 34816 B

  const int tid = threadIdx.x;
  const int r0  = blockIdx.x * 16;               // 16 rows, all in one t
  const int wid = tid >> 6;                      // wave 0..7 = k-split
  const int l   = tid & 63;
  const int lr  = l & 15;                        // frag row lane
  const int lk  = l >> 4;                        // frag k-octet lane

  const int kbeg = (wid < 7) ? wid * 96 : 672;   // splits {96x7, 112(+16 pad)}
  const int ccnt = (wid < 7) ? 3 : 4;

  f32x4 acc[4];
#pragma unroll
  for (int ct = 0; ct < 4; ++ct) acc[ct] = f32x4{0.f, 0.f, 0.f, 0.f};

  const float*  xr  = X + (size_t)(r0 + lr) * NIN;
  const short8* wp8 = (const short8*)W0p;
  const float4  z4  = {0.f, 0.f, 0.f, 0.f};

  for (int c = 0; c < ccnt; ++c) {
    const int g  = wid * 3 + c;                  // global 32-k chunk 0..24
    const int k0 = kbeg + c * 32 + lk * 8;

    // ---- A: 8 f32 (predicated pad tail), convert to bf16x3 in-register
    float4 xa, xb;
    if (k0 < NIN) {                              // k0 % 8 == 0 -> k0+8 <= 784
      xa = *(const float4*)(xr + k0);
      xb = *(const float4*)(xr + k0 + 4);
    } else {
      xa = xb = z4;
    }
    short8 af0, af1, af2;
    {
      float xs[8] = {xa.x, xa.y, xa.z, xa.w, xb.x, xb.y, xb.z, xb.w};
#pragma unroll
      for (int e = 0; e < 8; ++e) {
        float x  = xs[e];
        short h0 = bf16_rne(x);   float rr1 = x - bf16_val(h0);
        short h1 = bf16_rne(rr1); float rr2 = rr1 - bf16_val(h1);
        af0[e] = h0; af1[e] = h1; af2[e] = bf16_rne(rr2);
      }
    }

    // ---- per col-tile: load 3 B-frags (coalesced 1KB), 6 MFMAs (fixed order)
#pragma unroll
    for (int ct = 0; ct < 4; ++ct) {
      short8 bf0 = wp8[(size_t)((g * 3 + 0) * 4 + ct) * 64 + l];
      short8 bf1 = wp8[(size_t)((g * 3 + 1) * 4 + ct) * 64 + l];
      short8 bf2 = wp8[(size_t)((g * 3 + 2) * 4 + ct) * 64 + l];
      f32x4 a = acc[ct];
      a = __builtin_amdgcn_mfma_f32_16x16x32_bf16(af2, bf0, a, 0, 0, 0);
      a = __builtin_amdgcn_mfma_f32_16x16x32_bf16(af0, bf2, a, 0, 0, 0);
      a = __builtin_amdgcn_mfma_f32_16x16x32_bf16(af1, bf1, a, 0, 0, 0);
      a = __builtin_amdgcn_mfma_f32_16x16x32_bf16(af1, bf0, a, 0, 0, 0);
      a = __builtin_amdgcn_mfma_f32_16x16x32_bf16(af0, bf1, a, 0, 0, 0);
      a = __builtin_amdgcn_mfma_f32_16x16x32_bf16(af0, bf0, a, 0, 0, 0);
      acc[ct] = a;
    }
  }

  // ---- wave-partials -> LDS  (C/D: col = l&15, row = (l>>4)*4 + r)
#pragma unroll
  for (int ct = 0; ct < 4; ++ct)
#pragma unroll
    for (int r = 0; r < 4; ++r)
      red[wid][lk * 4 + r][ct * 16 + lr] = acc[ct][r];
  __syncthreads();

  // ---- reduce 8 partials (s ascending) + bias, write b-major I0T
  if (tid < 256) {
    const int t0  = r0 >> 8;
    const int bb0 = r0 & 255;
    int row = tid >> 4, q = tid & 15;
    float4 v = *(const float4*)&red[0][row][q * 4];
#pragma unroll
    for (int s = 1; s < 8; ++s) {
      float4 u = *(const float4*)&red[s][row][q * 4];
      v.x += u.x; v.y += u.y; v.z += u.z; v.w += u.w;
    }
    float4 bv = ((const float4*)b0)[q];
    v.x += bv.x; v.y += bv.y; v.z += bv.z; v.w += bv.w;
    ((float4*)I0T)[((size_t)(bb0 + row) * T_STEPS + t0) * 16 + q] = v;
  }
}

// ---------------------------------------------------------------------------
// Kernel 2: one block per batch element (R9's lean fused body, passed).
// ---------------------------------------------------------------------------
__global__ __launch_bounds__(256) void fused_kernel(
    const float* __restrict__ I0T,
    const float* __restrict__ W1, const float* __restrict__ b1,
    const float* __restrict__ W2, const float* __restrict__ b2,
    float* __restrict__ out) {
  __shared__ float bufA[112][68];
  __shared__ float sW1t[64][68];
  __shared__ float sW2[N2][68];
  __shared__ float sI2[T_STEPS][N2];

  const int b   = blockIdx.x;
  const int tid = threadIdx.x;
  const int j   = tid & 63;
  const int tq  = tid >> 6;
  float* outSpk = out;
  float* laySpk = out + T_STEPS * BATCH * N2;

  {
    const float4* src = (const float4*)I0T + (size_t)b * (T_STEPS * 16);
    for (int idx = tid; idx < T_STEPS * 16; idx += 256) {
      float4 v = src[idx];
      int t = idx >> 4, j4 = idx & 15;
      *(float4*)&bufA[t][j4 * 4] = v;
    }
  }
  __syncthreads();

  if (tq == 0) {
    float v = 0.0f;
#pragma unroll
    for (int g = 0; g < 4; ++g) {
      float ic[25];
#pragma unroll
      for (int i = 0; i < 25; ++i) ic[i] = bufA[g * 25 + i][j];
#pragma unroll
      for (int i = 0; i < 25; ++i) {
        v = v + 0.05f * ((0.0f - v) + ic[i]);
        float z = (v > 1.0f) ? 1.0f : 0.0f;
        v -= z;
        ic[i] = z;
      }
#pragma unroll
      for (int i = 0; i < 25; ++i) bufA[g * 25 + i][j] = ic[i];
    }
  } else {
    for (int idx = tid - 64; idx < 64 * 16; idx += 192) {
      int i = idx >> 4, jv = idx & 15;
      float4 wv = *(const float4*)(W1 + (size_t)i * 64 + jv * 4);
      sW1t[jv * 4 + 0][i] = wv.x;
      sW1t[jv * 4 + 1][i] = wv.y;
      sW1t[jv * 4 + 2][i] = wv.z;
      sW1t[jv * 4 + 3][i] = wv.w;
    }
    for (int idx = tid - 64; idx < N2 * 16; idx += 192) {
      int o = idx >> 4, jv = idx & 15;
      *(float4*)&sW2[o][jv * 4] = *(const float4*)(W2 + (size_t)o * 64 + jv * 4);
    }
  }
  __syncthreads();

  for (int idx = tid; idx < T_STEPS * 16; idx += 256) {
    int t = idx >> 4, jv = idx & 15;
    *(float4*)(laySpk + (size_t)t * CHUNK + b * 64 + jv * 4) =
        *(const float4*)&bufA[t][jv * 4];
  }

  const int iq = tid & 15;
  const int ts = tid >> 4;
  float g1[4][7];
  {
    float4 bias = *(const float4*)(b1 + iq * 4);
#pragma unroll
    for (int tt = 0; tt < 7; ++tt) {
      g1[0][tt] = bias.x; g1[1][tt] = bias.y; g1[2][tt] = bias.z; g1[3][tt] = bias.w;
    }
#pragma unroll
    for (int jq = 0; jq < 16; ++jq) {
      float4 zv4[7];
#pragma unroll
      for (int tt = 0; tt < 7; ++tt)
        zv4[tt] = *(const float4*)&bufA[ts * 7 + tt][jq * 4];
      float4 w4[4];
#pragma unroll
      for (int e = 0; e < 4; ++e)
        w4[e] = *(const float4*)&sW1t[jq * 4 + e][iq * 4];
#pragma unroll
      for (int e = 0; e < 4; ++e) {
#pragma unroll
        for (int tt = 0; tt < 7; ++tt) {
          float zv = ((const float*)&zv4[tt])[e];
          g1[0][tt] = fmaf(zv, w4[e].x, g1[0][tt]);
          g1[1][tt] = fmaf(zv, w4[e].y, g1[1][tt]);
          g1[2][tt] = fmaf(zv, w4[e].z, g1[2][tt]);
          g1[3][tt] = fmaf(zv, w4[e].w, g1[3][tt]);
        }
      }
    }
  }
  __syncthreads();
#pragma unroll
  for (int tt = 0; tt < 7; ++tt) {
    float4 o = {g1[0][tt], g1[1][tt], g1[2][tt], g1[3][tt]};
    *(float4*)&bufA[ts * 7 + tt][iq * 4] = o;
  }
  __syncthreads();

  if (tq == 0) {
    float v = 0.0f;
#pragma unroll
    for (int g = 0; g < 4; ++g) {
      float ic[25];
#pragma unroll
      for (int i = 0; i < 25; ++i) ic[i] = bufA[g * 25 + i][j];
#pragma unroll
      for (int i = 0; i < 25; ++i) {
        v = v + 0.05f * ((0.0f - v) + ic[i]);
        float z = (v > 1.0f) ? 1.0f : 0.0f;
        v -= z;
        ic[i] = z;
      }
#pragma unroll
      for (int i = 0; i < 25; ++i) bufA[g * 25 + i][j] = ic[i];
    }
  }
  __syncthreads();

  for (int idx = tid; idx < T_STEPS * 16; idx += 256) {
    int t = idx >> 4, jv = idx & 15;
    *(float4*)(laySpk + (size_t)t * CHUNK + BATCH * N0 + b * 64 + jv * 4) =
        *(const float4*)&bufA[t][jv * 4];
  }

  for (int idx = tid; idx < T_STEPS * N2; idx += 256) {
    int t = idx / N2, o = idx % N2;
    float a = b2[o];
#pragma unroll
    for (int jq = 0; jq < 16; ++jq) {
      float4 z = *(const float4*)&bufA[t][jq * 4];
      float4 wv = *(const float4*)&sW2[o][jq * 4];
      a += z.x * wv.x;
      a += z.y * wv.y;
      a += z.z * wv.z;
      a += z.w * wv.w;
    }
    sI2[t][o] = a;
  }
  __syncthreads();

  if (tid < N2) {
    float v = 0.0f;
#pragma unroll
    for (int g = 0; g < 4; ++g) {
      float ic[25];
#pragma unroll
      for (int i = 0; i < 25; ++i) ic[i] = sI2[g * 25 + i][tid];
#pragma unroll
      for (int i = 0; i < 25; ++i) {
        v = v + 0.05f * ((0.0f - v) + ic[i]);
        float z = (v > 1.0f) ? 1.0f : 0.0f;
        v -= z;
        ic[i] = z;
      }
#pragma unroll
      for (int i = 0; i < 25; ++i) sI2[g * 25 + i][tid] = ic[i];
    }
  }
  __syncthreads();

  for (int idx = tid; idx < T_STEPS * N2; idx += 256) {
    int t = idx / N2, o = idx % N2;
    float z = sI2[t][o];
    outSpk[(size_t)t * (BATCH * N2) + b * N2 + o] = z;
    laySpk[(size_t)t * CHUNK + BATCH * (N0 + N1) + b * N2 + o] = z;
  }
}

extern "C" void kernel_launch(void* const* d_in, const int* in_sizes, int n_in,
                              void* d_out, int out_size, void* d_ws, size_t ws_size,
                              hipStream_t stream) {
  const float* inp = (const float*)d_in[0];
  const float* W0  = (const float*)d_in[1];
  const float* b0  = (const float*)d_in[2];
  const float* W1  = (const float*)d_in[3];
  const float* b1  = (const float*)d_in[4];
  const float* W2  = (const float*)d_in[5];
  const float* b2  = (const float*)d_in[6];

  float* I0T = (float*)d_ws;                 // 6.55 MB, b-major [b][t][j]
  short* W0p = (short*)(I0T + I0ELEMS);      // 300 KB packed bf16x3 fragments

  prep_w0_pack<<<dim3(600), dim3(256), 0, stream>>>(W0, W0p);
  gemm0_kernel<<<dim3(1600), dim3(512), 0, stream>>>(inp, W0p, b0, I0T);
  fused_kernel<<<dim3(BATCH), dim3(256), 0, stream>>>(I0T, W1, b1, W2, b2,
                                                      (float*)d_out);
}